// Round 3
// baseline (174.968 us; speedup 1.0000x reference)
//
#include <hip/hip_runtime.h>
#include <math.h>

#define NTOK  16384   // 4 * 4096 tokens
#define DK    2048    // d_model
#define NEXP  64
#define TPW   16      // tokens per wave
#define KC    32      // k per chunk
#define KHALF 1024    // K range per wave (K split 2-way across wave pair)
#define NIT   (KHALF / KC)   // 32 chunks

// Async global->LDS, 16B/lane: HW writes dst + lane*16 (wave-uniform dst base).
__device__ __forceinline__ void gload_lds16(const float* src, float* dst) {
    __builtin_amdgcn_global_load_lds(
        (const __attribute__((address_space(1))) void*)src,
        (__attribute__((address_space(3))) void*)dst, 16, 0, 0);
}

// One K-chunk: acc[t] += dot(x[t][k0..k0+31], W[lane][k0..k0+31]).
// xb4 layout: [t][q] float4, uniform address per (t,q) -> broadcast ds_read_b128.
__device__ __forceinline__ void compute_chunk(const float4* xb4, const float4 wv[8],
                                              float acc[TPW]) {
    #pragma unroll
    for (int t = 0; t < TPW; ++t) {
        #pragma unroll
        for (int q = 0; q < 8; ++q) {
            const float4 xv = xb4[t * 8 + q];
            acc[t] = fmaf(xv.x, wv[q].x, acc[t]);
            acc[t] = fmaf(xv.y, wv[q].y, acc[t]);
            acc[t] = fmaf(xv.z, wv[q].z, acc[t]);
            acc[t] = fmaf(xv.w, wv[q].w, acc[t]);
        }
    }
}

__global__ __launch_bounds__(256, 2) void topk_router_kernel(
    const float* __restrict__ x,     // [NTOK][DK]
    const float* __restrict__ Wg,    // [NEXP][DK]
    float* __restrict__ out)         // [NTOK*2] indices (as float) ++ [NTOK*2] weights
{
    // Wave-private x staging (no block sharing -> no barriers in main loop).
    __shared__ float xs[4][2][TPW * KC];     // 4 waves x dbuf x 2KB = 16 KiB
    __shared__ float lg[2][TPW][NEXP + 1];   // pair-combine logits, 8.1 KiB

    const int tid  = threadIdx.x;
    const int w    = tid >> 6;     // wave 0..3
    const int lane = tid & 63;     // lane == expert index
    const int pair = w >> 1;       // two waves share 16 tokens, split K
    const int h    = w & 1;        // K-half
    const int tok0 = blockIdx.x * (2 * TPW) + pair * TPW;

    // Per-lane W row (expert = lane), this wave's K-half.
    const float* wrow = Wg + (size_t)lane * DK + h * KHALF;
    // x staging source: lane -> token (lane>>3), k-quad (lane&7). 128B/token rows.
    const float* xsrc = x + (size_t)(tok0 + (lane >> 3)) * DK + h * KHALF + (lane & 7) * 4;

    float* xb0 = &xs[w][0][0];
    float* xb1 = &xs[w][1][0];

    float acc[TPW];
    #pragma unroll
    for (int t = 0; t < TPW; ++t) acc[t] = 0.f;

    float4 wa[8], wb[8];

    // ---- prologue: issue chunk 0 (buf0, wa) then chunk 1 (buf1, wb) ----
    // FIFO issue order per chunk-set: [x (2), W (8)] => vmcnt(10) drains one set.
    gload_lds16(xsrc,           xb0);
    gload_lds16(xsrc + 8 * DK,  xb0 + 8 * KC);
    #pragma unroll
    for (int q = 0; q < 8; ++q) wa[q] = *(const float4*)(wrow + q * 4);
    gload_lds16(xsrc + KC,          xb1);
    gload_lds16(xsrc + 8 * DK + KC, xb1 + 8 * KC);
    #pragma unroll
    for (int q = 0; q < 8; ++q) wb[q] = *(const float4*)(wrow + KC + q * 4);

    #pragma unroll 1
    for (int i = 0; i < NIT - 2; i += 2) {
        // ---- phase A: compute chunk i (buf0, wa); prefetch chunk i+2 ----
        // outstanding here: set(i)=10 oldest + set(i+1)=10 -> vmcnt(10) drains set(i).
        asm volatile("s_waitcnt vmcnt(10)" ::: "memory");
        __builtin_amdgcn_sched_barrier(0);
        compute_chunk((const float4*)xb0, wa, acc);
        __builtin_amdgcn_sched_barrier(0);
        {
            const float* s = xsrc + (size_t)(i + 2) * KC;
            gload_lds16(s,          xb0);
            gload_lds16(s + 8 * DK, xb0 + 8 * KC);
            const float* wr = wrow + (i + 2) * KC;
            #pragma unroll
            for (int q = 0; q < 8; ++q) wa[q] = *(const float4*)(wr + q * 4);
        }
        // ---- phase B: compute chunk i+1 (buf1, wb); prefetch chunk i+3 ----
        asm volatile("s_waitcnt vmcnt(10)" ::: "memory");
        __builtin_amdgcn_sched_barrier(0);
        compute_chunk((const float4*)xb1, wb, acc);
        __builtin_amdgcn_sched_barrier(0);
        {
            const float* s = xsrc + (size_t)(i + 3) * KC;
            gload_lds16(s,          xb1);
            gload_lds16(s + 8 * DK, xb1 + 8 * KC);
            const float* wr = wrow + (i + 3) * KC;
            #pragma unroll
            for (int q = 0; q < 8; ++q) wb[q] = *(const float4*)(wr + q * 4);
        }
    }
    // ---- tail: chunks NIT-2 (outstanding 20 -> vmcnt(10)) and NIT-1 (vmcnt(0)) ----
    asm volatile("s_waitcnt vmcnt(10)" ::: "memory");
    __builtin_amdgcn_sched_barrier(0);
    compute_chunk((const float4*)xb0, wa, acc);
    asm volatile("s_waitcnt vmcnt(0)" ::: "memory");
    __builtin_amdgcn_sched_barrier(0);
    compute_chunk((const float4*)xb1, wb, acc);

    // ---- combine K-halves (the only block barrier) ----
    __syncthreads();
    if (h == 0) {
        #pragma unroll
        for (int t = 0; t < TPW; ++t) lg[pair][t][lane] = acc[t];
    }
    __syncthreads();
    if (h == 1) {
        #pragma unroll 1
        for (int t = 0; t < TPW; ++t) {
            const float v = lg[pair][t][lane] + acc[t];

            // top-1 (tie -> lower index, matching lax.top_k)
            float m1 = v; int i1 = lane;
            #pragma unroll
            for (int off = 32; off > 0; off >>= 1) {
                float ov = __shfl_xor(m1, off);
                int   oi = __shfl_xor(i1, off);
                if (ov > m1 || (ov == m1 && oi < i1)) { m1 = ov; i1 = oi; }
            }
            // top-2: mask out winner
            float m2 = (lane == i1) ? -INFINITY : v; int i2 = lane;
            #pragma unroll
            for (int off = 32; off > 0; off >>= 1) {
                float ov = __shfl_xor(m2, off);
                int   oi = __shfl_xor(i2, off);
                if (ov > m2 || (ov == m2 && oi < i2)) { m2 = ov; i2 = oi; }
            }

            if (lane == 0) {
                const int gtok = tok0 + t;
                // softmax denom cancels: w1 = 1/(1+e^{l2-l1}), w2 = 1 - w1
                const float e  = expf(m2 - m1);
                const float w1 = 1.0f / (1.0f + e);
                const float w2 = e / (1.0f + e);
                out[gtok * 2 + 0] = (float)i1;
                out[gtok * 2 + 1] = (float)i2;
                out[NTOK * 2 + gtok * 2 + 0] = w1;
                out[NTOK * 2 + gtok * 2 + 1] = w2;
            }
        }
    }
}

extern "C" void kernel_launch(void* const* d_in, const int* in_sizes, int n_in,
                              void* d_out, int out_size, void* d_ws, size_t ws_size,
                              hipStream_t stream) {
    const float* x  = (const float*)d_in[0];
    const float* Wg = (const float*)d_in[1];
    float* out = (float*)d_out;
    // 512 blocks x 256 threads: 2048 waves, 2 blocks/CU, wave-private pipelines.
    hipLaunchKernelGGL(topk_router_kernel, dim3(NTOK / (2 * TPW)), dim3(256), 0, stream,
                       x, Wg, out);
}